// Round 12
// baseline (27913.098 us; speedup 1.0000x reference)
//
#include <hip/hip_runtime.h>

typedef unsigned u2v __attribute__((ext_vector_type(2)));

// ---- XOR-butterfly reduction, all-VALU (proven bit-uniform, R5/R6/R8/R10)
template<int CTRL>
__device__ __forceinline__ float dpp_xadd(float v) {
    int s = __builtin_amdgcn_update_dpp(0, __float_as_int(v), CTRL, 0xF, 0xF, true);
    return v + __int_as_float(s);
}

#if __has_builtin(__builtin_amdgcn_permlane16_swap)
__device__ __forceinline__ float xor16_add(float v) {
    u2v r = __builtin_amdgcn_permlane16_swap((unsigned)__float_as_int(v),
                                             (unsigned)__float_as_int(v),
                                             false, false);
    return __int_as_float((int)r.x) + __int_as_float((int)r.y);
}
#else
__device__ __forceinline__ float xor16_add(float v) {
    int s = __builtin_amdgcn_ds_swizzle(__float_as_int(v), 0x401F);
    return v + __int_as_float(s);
}
#endif

__device__ __forceinline__ float red32(float v) {
    v = dpp_xadd<0xB1>(v);    // lane ^ 1
    v = dpp_xadd<0x4E>(v);    // lane ^ 2
    v = dpp_xadd<0x141>(v);   // lane ^ 7
    v = dpp_xadd<0x140>(v);   // lane ^ 15
    v = xor16_add(v);         // lane ^ 16
    return v;
}

// ---- parallel precompute: s_n = LRW/(sum|u_n|^2+eps); sC_n = s_n*C_n ----
__global__ void pre_tab(const float* __restrict__ xre,
                        const float* __restrict__ xim,
                        float4* __restrict__ tab, int ns) {
    int n = blockIdx.x * blockDim.x + threadIdx.x;
    if (n >= ns) return;
    const float* ar = xre + 4 * n;
    const float* ai = xim + 4 * n;
    float un = 0.f;
    #pragma unroll 8
    for (int k = 0; k < 64; ++k) un = fmaf(ar[k], ar[k], fmaf(ai[k], ai[k], un));
    float s = (1.0f / 64.0f) / (un + 1e-8f);
    float cr = 0.f, ci = 0.f;
    if (n + 1 < ns) {
        const float* br_ = ar + 4;
        const float* bi_ = ai + 4;
        #pragma unroll 8
        for (int k = 0; k < 64; ++k) {
            cr = fmaf(ar[k], br_[k], fmaf(ai[k], bi_[k], cr));
            ci = fmaf(ar[k], bi_[k], ci);
            ci = fmaf(-ai[k], br_[k], ci);
        }
    }
    tab[n] = make_float4(s, s * cr, s * ci, 0.f);
}

// ---- DDLMS scan: one wave64; v split base+delta; pinned dist-3 prefetch -
template<bool PRE>
__global__ __launch_bounds__(64, 1)
void ddlms_scan(const float* __restrict__ xre,
                const float* __restrict__ xim,
                const float4* __restrict__ tab,
                float* __restrict__ out) {
    const int l = (int)threadIdx.x;
    const int m = l & 31;
    const int half = l >> 5;

    constexpr float EPSv = 1e-8f;
    constexpr float LRW  = 1.0f / 64.0f;
    constexpr float LRF  = 1.0f / 128.0f;
    constexpr float LRB  = 1.0f / 2048.0f;
    const float B1 = 0.6324555320336759f;
    const float A1 = 0.31622776601683794f;
    const float A3 = 0.9486832980505138f;

    float wAr=0.f, wAi=0.f, wBr=0.f, wBi=0.f;
    float fr=1.f, fi=0.f, br=0.f, bi=0.f;
    float psr=1.f, psj=0.f;
    float vr=0.f, vi=0.f;
    float ewPr=0.f, ewPi=0.f, sP=0.f;

    float2* __restrict__ o2 = reinterpret_cast<float2*>(out);
    const int NS = 99985;

    auto LOADU = [&](int nn, float& a, float& b_, float& c, float& d_) {
        const float* pr = xre + 4 * nn;
        const float* pi = xim + 4 * nn;
        a = pr[m]; c = pr[m + 32]; b_ = pi[m]; d_ = pi[m + 32];
    };
    auto LOADT = [&](int nn, float& s, float& cr, float& ci) {
        if constexpr (PRE) {
            float4 t = tab[nn];
            s = t.x; cr = t.y; ci = t.z;
        }
    };

    // 4 rotating u slots (slot k holds u_n with n%4==k) and 4 t slots
    float u0Ar,u0Ai,u0Br,u0Bi, u1Ar,u1Ai,u1Br,u1Bi,
          u2Ar,u2Ai,u2Br,u2Bi, u3Ar,u3Ai,u3Br,u3Bi;
    float t0s=0,t0r=0,t0i=0, t1s=0,t1r=0,t1i=0,
          t2s=0,t2r=0,t2i=0, t3s=0,t3r=0,t3i=0;

    u3Ar=u3Ai=u3Br=u3Bi=0.f;                 // uP for step 0 (sP=0)
    LOADU(0, u0Ar,u0Ai,u0Br,u0Bi);
    LOADU(1, u1Ar,u1Ai,u1Br,u1Bi);
    LOADU(2, u2Ar,u2Ai,u2Br,u2Bi);
    LOADT(0, t0s,t0r,t0i);
    LOADT(1, t1s,t1r,t1i);
    LOADT(2, t2s,t2r,t2i);

    // STEP(n): uP = slot (n-1)%4 (read u_{n-1}, then prefetch u_{n+3} into
    // it); uC = slot n%4 (non-PRE only); uN = slot (n+1)%4; tC = t slot n%4;
    // tF = t slot (n+3)%4. uQ/tQ = slot (n+2)%4 — the slot LOADED during
    // STEP(n-1); the empty "+v" asm pins those loads early (defeats the
    // compiler's load-sinking, VGPR=36 evidence) and forces their waitcnt
    // here, one full step (~500 cy) after issue -> free.
    auto STEP = [&](int n,
        float& uPAr, float& uPAi, float& uPBr, float& uPBi,
        float& uCAr, float& uCAi, float& uCBr, float& uCBi,
        float& uNAr, float& uNAi, float& uNBr, float& uNBi,
        float& uQAr, float& uQAi, float& uQBr, float& uQBi,
        float& tCs, float& tCr, float& tCi,
        float& tFs, float& tFr, float& tFi,
        float& tQs, float& tQr, float& tQi) {

        // liveness pin (zero instructions)
        asm volatile("" : "+v"(uQAr), "+v"(uQAi), "+v"(uQBr), "+v"(uQBi),
                          "+v"(tQs), "+v"(tQr), "+v"(tQi));

        // shadow: w += sP*(ewP (x) conj(uP))   (only reader of the uP slot)
        {
            float gr = ewPr * uPAr; gr = fmaf( ewPi, uPAi, gr);
            float gi = ewPi * uPAr; gi = fmaf(-ewPr, uPAi, gi);
            wAr = fmaf(sP, gr, wAr); wAi = fmaf(sP, gi, wAi);
            float hr = ewPr * uPBr; hr = fmaf( ewPi, uPBi, hr);
            float hi = ewPi * uPBr; hi = fmaf(-ewPr, uPBi, hi);
            wBr = fmaf(sP, hr, wBr); wBi = fmaf(sP, hi, wBi);
        }

        // distance-3 prefetch into the now-dead uP/tF slots
        {
            int nn = n + 3; if (nn > NS - 1) nn = NS - 1;
            LOADU(nn, uPAr, uPAi, uPBr, uPBi);
            LOADT(nn, tFs, tFr, tFi);
        }

        // shadow: base_{n+1} = red(w_n * u_{n+1})
        float basr, basi;
        {
            float prr = wAr * uNAr; prr = fmaf(-wAi, uNAi, prr);
            prr = fmaf(wBr, uNBr, prr); prr = fmaf(-wBi, uNBi, prr);
            float pri = wAr * uNAi; pri = fmaf( wAi, uNAr, pri);
            pri = fmaf(wBr, uNBi, pri); pri = fmaf( wBi, uNBr, pri);
            basr = red32(prr); basi = red32(pri);
        }

        // per-step scalars
        float sN, sCr, sCi;
        if constexpr (PRE) {
            sN = tCs; sCr = tCr; sCi = tCi;
        } else {
            float uu = uCAr * uCAr; uu = fmaf(uCAi, uCAi, uu);
            uu = fmaf(uCBr, uCBr, uu); uu = fmaf(uCBi, uCBi, uu);
            sN = LRW * __builtin_amdgcn_rcpf(red32(uu) + EPSv);
            float ccr = uCAr * uNAr; ccr = fmaf(uCAi, uNAi, ccr);
            ccr = fmaf(uCBr, uNBr, ccr); ccr = fmaf(uCBi, uNBi, ccr);
            float cci = uCAr * uNAi; cci = fmaf(-uCAi, uNAr, cci);
            cci = fmaf(uCBr, uNBi, cci); cci = fmaf(-uCBi, uNBr, cci);
            sCr = sN * red32(ccr); sCi = sN * red32(cci);
        }

        // ---- critical chain (byte-identical dataflow to R8/R10) ----
        float kr = fmaf(vr, fr, -(vi * fi));
        float ki = fmaf(vr, fi,   vi * fr);
        float zr = kr + br, zi = ki + bi;
        if (m == 0) o2[2 * n + half] = make_float2(zr, zi);

        float magr = (fabsf(zr) > B1) ? A3 : A1;
        float dr   = (zr <= 0.f) ? -magr : magr;
        float magi = (fabsf(zi) > B1) ? A3 : A1;
        float di   = (zi <= 0.f) ? -magi : magi;

        float er = dr - zr, ei = di - zi;

        float v2  = fmaf(vr, vr, fmaf(vi, vi, EPSv));
        float rv  = __builtin_amdgcn_rcpf(v2);
        float gfr = fmaf(er, vr,   ei * vi)  * rv;
        float gfi = fmaf(ei, vr, -(er * vi)) * rv;
        float m2  = fmaf(gfr, gfr, gfi * gfi);
        float scf = fminf(1.f, 30.f * __builtin_amdgcn_rsqf(m2));
        float tf  = LRF * scf;

        float dbr = dr - br, dbi = di - bi;
        float ewr = fmaf(dbr, psr, -(dbi * psj)) - vr;
        float ewi = fmaf(dbr, psj,   dbi * psr)  - vi;

        float Dr = fmaf(ewr, sCr, -(ewi * sCi));
        float Di = fmaf(ewr, sCi,   ewi * sCr);
        vr = basr + Dr;
        vi = basi + Di;

        fr = fmaf(tf, gfr, fr); fi = fmaf(tf, gfi, fi);
        br = fmaf(LRB, er, br); bi = fmaf(LRB, ei, bi);

        float ff = fmaf(fr, fr, fi * fi);
        float rs = __builtin_amdgcn_rsqf(ff);
        psr = fr * rs; psj = -(fi * rs);

        ewPr = ewr; ewPi = ewi; sP = sN;
    };

    int n = 0;
    for (int it = 0; it < 24996; ++it) {     // 4*24996 = 99984 steps
        STEP(n+0, u3Ar,u3Ai,u3Br,u3Bi, u0Ar,u0Ai,u0Br,u0Bi,
                  u1Ar,u1Ai,u1Br,u1Bi, u2Ar,u2Ai,u2Br,u2Bi,
                  t0s,t0r,t0i, t3s,t3r,t3i, t2s,t2r,t2i);
        STEP(n+1, u0Ar,u0Ai,u0Br,u0Bi, u1Ar,u1Ai,u1Br,u1Bi,
                  u2Ar,u2Ai,u2Br,u2Bi, u3Ar,u3Ai,u3Br,u3Bi,
                  t1s,t1r,t1i, t0s,t0r,t0i, t3s,t3r,t3i);
        STEP(n+2, u1Ar,u1Ai,u1Br,u1Bi, u2Ar,u2Ai,u2Br,u2Bi,
                  u3Ar,u3Ai,u3Br,u3Bi, u0Ar,u0Ai,u0Br,u0Bi,
                  t2s,t2r,t2i, t1s,t1r,t1i, t0s,t0r,t0i);
        STEP(n+3, u2Ar,u2Ai,u2Br,u2Bi, u3Ar,u3Ai,u3Br,u3Bi,
                  u0Ar,u0Ai,u0Br,u0Bi, u1Ar,u1Ai,u1Br,u1Bi,
                  t3s,t3r,t3i, t2s,t2r,t2i, t1s,t1r,t1i);
        n += 4;
    }
    // tail step 99984 (k=0 pattern; prefetch clamps to 99984)
    STEP(99984, u3Ar,u3Ai,u3Br,u3Bi, u0Ar,u0Ai,u0Br,u0Bi,
                u1Ar,u1Ai,u1Br,u1Bi, u2Ar,u2Ai,u2Br,u2Bi,
                t0s,t0r,t0i, t3s,t3r,t3i, t2s,t2r,t2i);
}

extern "C" void kernel_launch(void* const* d_in, const int* in_sizes, int n_in,
                              void* d_out, int out_size, void* d_ws, size_t ws_size,
                              hipStream_t stream) {
    const float* xre = (const float*)d_in[0];
    const float* xim = (const float*)d_in[1];
    float* out = (float*)d_out;
    const int NS = 99985;

    if (ws_size >= (size_t)NS * sizeof(float4)) {
        float4* tab = (float4*)d_ws;
        pre_tab<<<(NS + 255) / 256, 256, 0, stream>>>(xre, xim, tab, NS);
        ddlms_scan<true><<<1, 64, 0, stream>>>(xre, xim, tab, out);
    } else {
        ddlms_scan<false><<<1, 64, 0, stream>>>(xre, xim, nullptr, out);
    }
}

// Round 13
// 25855.453 us; speedup vs baseline: 1.0796x; 1.0796x over previous
//
#include <hip/hip_runtime.h>

typedef unsigned u2v __attribute__((ext_vector_type(2)));

// ---- XOR-butterfly reduction: FUSED DPP adds (1 instr/stage) ------------
// v_add_f32 dst, dpp(v), v  == add(v[l^k], v[l]) — operand-order swap vs the
// mov_dpp+add form: commutative-exact, bit-identical across lanes (R3/R5
// proven class). Plain asm (non-volatile) -> fully schedulable.
__device__ __forceinline__ float dppadd_x1(float v) {
    float r; asm("v_add_f32 %0, %1, %1 quad_perm:[1,0,3,2] row_mask:0xf bank_mask:0xf"
                 : "=v"(r) : "v"(v)); return r;
}
__device__ __forceinline__ float dppadd_x2(float v) {
    float r; asm("v_add_f32 %0, %1, %1 quad_perm:[2,3,0,1] row_mask:0xf bank_mask:0xf"
                 : "=v"(r) : "v"(v)); return r;
}
__device__ __forceinline__ float dppadd_x7(float v) {
    float r; asm("v_add_f32 %0, %1, %1 row_half_mirror row_mask:0xf bank_mask:0xf"
                 : "=v"(r) : "v"(v)); return r;
}
__device__ __forceinline__ float dppadd_x15(float v) {
    float r; asm("v_add_f32 %0, %1, %1 row_mirror row_mask:0xf bank_mask:0xf"
                 : "=v"(r) : "v"(v)); return r;
}

#if __has_builtin(__builtin_amdgcn_permlane16_swap)
__device__ __forceinline__ float xor16_add(float v) {
    u2v r = __builtin_amdgcn_permlane16_swap((unsigned)__float_as_int(v),
                                             (unsigned)__float_as_int(v),
                                             false, false);
    return __int_as_float((int)r.x) + __int_as_float((int)r.y);
}
#else
__device__ __forceinline__ float xor16_add(float v) {
    int s = __builtin_amdgcn_ds_swizzle(__float_as_int(v), 0x401F);
    return v + __int_as_float(s);
}
#endif

__device__ __forceinline__ float red32(float v) {
    v = dppadd_x1(v);
    v = dppadd_x2(v);
    v = dppadd_x7(v);
    v = dppadd_x15(v);
    v = xor16_add(v);
    return v;
}

// ---- parallel precompute: s_n = LRW/(sum|u_n|^2+eps); sC_n = s_n*C_n ----
__global__ void pre_tab(const float* __restrict__ xre,
                        const float* __restrict__ xim,
                        float4* __restrict__ tab, int ns) {
    int n = blockIdx.x * blockDim.x + threadIdx.x;
    if (n >= ns) return;
    const float* ar = xre + 4 * n;
    const float* ai = xim + 4 * n;
    float un = 0.f;
    #pragma unroll 8
    for (int k = 0; k < 64; ++k) un = fmaf(ar[k], ar[k], fmaf(ai[k], ai[k], un));
    float s = (1.0f / 64.0f) / (un + 1e-8f);
    float cr = 0.f, ci = 0.f;
    if (n + 1 < ns) {
        const float* br_ = ar + 4;
        const float* bi_ = ai + 4;
        #pragma unroll 8
        for (int k = 0; k < 64; ++k) {
            cr = fmaf(ar[k], br_[k], fmaf(ai[k], bi_[k], cr));
            ci = fmaf(ar[k], bi_[k], ci);
            ci = fmaf(-ai[k], br_[k], ci);
        }
    }
    tab[n] = make_float4(s, s * cr, s * ci, 0.f);
}

// ---- DDLMS scan: one wave64; no divergent store (z-latch + bulk flush) --
template<bool PRE>
__global__ __launch_bounds__(64, 1)
void ddlms_scan(const float* __restrict__ xre,
                const float* __restrict__ xim,
                const float4* __restrict__ tab,
                float* __restrict__ out) {
    const int l = (int)threadIdx.x;
    const int m = l & 31;
    const int half = l >> 5;

    constexpr float EPSv = 1e-8f;
    constexpr float LRW  = 1.0f / 64.0f;
    constexpr float LRF  = 1.0f / 128.0f;
    constexpr float LRB  = 1.0f / 2048.0f;
    const float B1 = 0.6324555320336759f;
    const float A1 = 0.31622776601683794f;
    const float A3 = 0.9486832980505138f;

    float wAr=0.f, wAi=0.f, wBr=0.f, wBi=0.f;
    float fr=1.f, fi=0.f, br=0.f, bi=0.f;
    float psr=1.f, psj=0.f;
    float vr=0.f, vi=0.f;
    float ewPr=0.f, ewPi=0.f, sP=0.f;
    float zsr=0.f, zsi=0.f;                  // per-lane z latch (step n&31 == m)

    float2* __restrict__ o2 = reinterpret_cast<float2*>(out);
    const int NS = 99985;

    auto LOADU = [&](int nn, float& a, float& b_, float& c, float& d_) {
        const float* pr = xre + 4 * nn;
        const float* pi = xim + 4 * nn;
        a = pr[m]; c = pr[m + 32]; b_ = pi[m]; d_ = pi[m + 32];
    };
    auto LOADT = [&](int nn, float& s, float& cr, float& ci) {
        if constexpr (PRE) {
            float4 t = tab[nn];
            s = t.x; cr = t.y; ci = t.z;
        }
    };

    float u0Ar,u0Ai,u0Br,u0Bi, u1Ar,u1Ai,u1Br,u1Bi,
          u2Ar,u2Ai,u2Br,u2Bi, u3Ar,u3Ai,u3Br,u3Bi;
    float t0s=0,t0r=0,t0i=0, t1s=0,t1r=0,t1i=0,
          t2s=0,t2r=0,t2i=0, t3s=0,t3r=0,t3i=0;

    u3Ar=u3Ai=u3Br=u3Bi=0.f;                 // uP for step 0 (sP=0)
    LOADU(0, u0Ar,u0Ai,u0Br,u0Bi);
    LOADU(1, u1Ar,u1Ai,u1Br,u1Bi);
    LOADU(2, u2Ar,u2Ai,u2Br,u2Bi);
    LOADT(0, t0s,t0r,t0i);
    LOADT(1, t1s,t1r,t1i);
    LOADT(2, t2s,t2r,t2i);

    auto STEP = [&](int n,
        float& uPAr, float& uPAi, float& uPBr, float& uPBi,
        float& uCAr, float& uCAi, float& uCBr, float& uCBi,
        float& uNAr, float& uNAi, float& uNBr, float& uNBi,
        float& tCs, float& tCr, float& tCi,
        float& tFs, float& tFr, float& tFi) {

        // shadow: w += sP*(ewP (x) conj(uP))
        {
            float gr = ewPr * uPAr; gr = fmaf( ewPi, uPAi, gr);
            float gi = ewPi * uPAr; gi = fmaf(-ewPr, uPAi, gi);
            wAr = fmaf(sP, gr, wAr); wAi = fmaf(sP, gi, wAi);
            float hr = ewPr * uPBr; hr = fmaf( ewPi, uPBi, hr);
            float hi = ewPi * uPBr; hi = fmaf(-ewPr, uPBi, hi);
            wBr = fmaf(sP, hr, wBr); wBi = fmaf(sP, hi, wBi);
        }

        // distance-3 prefetch into the now-dead uP/tF slots
        {
            int nn = n + 3; if (nn > NS - 1) nn = NS - 1;
            LOADU(nn, uPAr, uPAi, uPBr, uPBi);
            LOADT(nn, tFs, tFr, tFi);
        }

        // shadow: base_{n+1} = red(w_n * u_{n+1})
        float basr, basi;
        {
            float prr = wAr * uNAr; prr = fmaf(-wAi, uNAi, prr);
            prr = fmaf(wBr, uNBr, prr); prr = fmaf(-wBi, uNBi, prr);
            float pri = wAr * uNAi; pri = fmaf( wAi, uNAr, pri);
            pri = fmaf(wBr, uNBi, pri); pri = fmaf( wBi, uNBr, pri);
            basr = red32(prr); basi = red32(pri);
        }

        // per-step scalars
        float sN, sCr, sCi;
        if constexpr (PRE) {
            sN = tCs; sCr = tCr; sCi = tCi;
        } else {
            float uu = uCAr * uCAr; uu = fmaf(uCAi, uCAi, uu);
            uu = fmaf(uCBr, uCBr, uu); uu = fmaf(uCBi, uCBi, uu);
            sN = LRW * __builtin_amdgcn_rcpf(red32(uu) + EPSv);
            float ccr = uCAr * uNAr; ccr = fmaf(uCAi, uNAi, ccr);
            ccr = fmaf(uCBr, uNBr, ccr); ccr = fmaf(uCBi, uNBi, ccr);
            float cci = uCAr * uNAi; cci = fmaf(-uCAi, uNAr, cci);
            cci = fmaf(uCBr, uNBi, cci); cci = fmaf(-uCBi, uNBr, cci);
            sCr = sN * red32(ccr); sCi = sN * red32(cci);
        }

        // ---- critical chain (values identical to R8/R10) ----
        float kr = fmaf(vr, fr, -(vi * fi));
        float ki = fmaf(vr, fi,   vi * fr);
        float zr = kr + br, zi = ki + bi;

        // z-latch instead of divergent store: no exec-mask wall
        {
            bool c = (m == (n & 31));
            zsr = c ? zr : zsr;
            zsi = c ? zi : zsi;
        }

        float magr = (fabsf(zr) > B1) ? A3 : A1;
        float dr   = (zr <= 0.f) ? -magr : magr;
        float magi = (fabsf(zi) > B1) ? A3 : A1;
        float di   = (zi <= 0.f) ? -magi : magi;

        float er = dr - zr, ei = di - zi;

        float v2  = fmaf(vr, vr, fmaf(vi, vi, EPSv));
        float rv  = __builtin_amdgcn_rcpf(v2);
        float gfr = fmaf(er, vr,   ei * vi)  * rv;
        float gfi = fmaf(ei, vr, -(er * vi)) * rv;
        float m2  = fmaf(gfr, gfr, gfi * gfi);
        float scf = fminf(1.f, 30.f * __builtin_amdgcn_rsqf(m2));
        float tf  = LRF * scf;

        float dbr = dr - br, dbi = di - bi;
        float ewr = fmaf(dbr, psr, -(dbi * psj)) - vr;
        float ewi = fmaf(dbr, psj,   dbi * psr)  - vi;

        float Dr = fmaf(ewr, sCr, -(ewi * sCi));
        float Di = fmaf(ewr, sCi,   ewi * sCr);
        vr = basr + Dr;
        vi = basi + Di;

        fr = fmaf(tf, gfr, fr); fi = fmaf(tf, gfi, fi);
        br = fmaf(LRB, er, br); bi = fmaf(LRB, ei, bi);

        float ff = fmaf(fr, fr, fi * fi);
        float rs = __builtin_amdgcn_rsqf(ff);
        psr = fr * rs; psj = -(fi * rs);

        ewPr = ewr; ewPi = ewi; sP = sN;
    };

    #define STEP4()                                                        \
        STEP(n+0, u3Ar,u3Ai,u3Br,u3Bi, u0Ar,u0Ai,u0Br,u0Bi,               \
                  u1Ar,u1Ai,u1Br,u1Bi, t0s,t0r,t0i, t3s,t3r,t3i);         \
        STEP(n+1, u0Ar,u0Ai,u0Br,u0Bi, u1Ar,u1Ai,u1Br,u1Bi,               \
                  u2Ar,u2Ai,u2Br,u2Bi, t1s,t1r,t1i, t0s,t0r,t0i);         \
        STEP(n+2, u1Ar,u1Ai,u1Br,u1Bi, u2Ar,u2Ai,u2Br,u2Bi,               \
                  u3Ar,u3Ai,u3Br,u3Bi, t2s,t2r,t2i, t1s,t1r,t1i);         \
        STEP(n+3, u2Ar,u2Ai,u2Br,u2Bi, u3Ar,u3Ai,u3Br,u3Bi,               \
                  u0Ar,u0Ai,u0Br,u0Bi, t3s,t3r,t3i, t2s,t2r,t2i);         \
        n += 4

    int n = 0;
    // main: 3124 blocks of 32 steps, full-exec flush per block
    for (int big = 0; big < 3124; ++big) {
        for (int j8 = 0; j8 < 8; ++j8) { STEP4(); }
        float2 val; val.x = zsr; val.y = zsi;
        o2[2 * (n - 32 + m) + half] = val;          // all 64 lanes, coalesced
    }
    // tail: 17 steps (n = 99968 .. 99984)
    for (int j8 = 0; j8 < 4; ++j8) { STEP4(); }
    STEP(99984, u3Ar,u3Ai,u3Br,u3Bi, u0Ar,u0Ai,u0Br,u0Bi,
                u1Ar,u1Ai,u1Br,u1Bi, t0s,t0r,t0i, t3s,t3r,t3i);
    if (m <= 16) {                                   // one masked flush at end
        float2 val; val.x = zsr; val.y = zsi;
        o2[2 * (99968 + m) + half] = val;
    }
    #undef STEP4
}

extern "C" void kernel_launch(void* const* d_in, const int* in_sizes, int n_in,
                              void* d_out, int out_size, void* d_ws, size_t ws_size,
                              hipStream_t stream) {
    const float* xre = (const float*)d_in[0];
    const float* xim = (const float*)d_in[1];
    float* out = (float*)d_out;
    const int NS = 99985;

    if (ws_size >= (size_t)NS * sizeof(float4)) {
        float4* tab = (float4*)d_ws;
        pre_tab<<<(NS + 255) / 256, 256, 0, stream>>>(xre, xim, tab, NS);
        ddlms_scan<true><<<1, 64, 0, stream>>>(xre, xim, tab, out);
    } else {
        ddlms_scan<false><<<1, 64, 0, stream>>>(xre, xim, nullptr, out);
    }
}

// Round 14
// 19634.332 us; speedup vs baseline: 1.4216x; 1.3168x over previous
//
#include <hip/hip_runtime.h>

typedef unsigned u2v __attribute__((ext_vector_type(2)));

// ---- XOR-butterfly reduction, all-VALU builtins (R10-exact, proven) -----
template<int CTRL>
__device__ __forceinline__ float dpp_xadd(float v) {
    int s = __builtin_amdgcn_update_dpp(0, __float_as_int(v), CTRL, 0xF, 0xF, true);
    return v + __int_as_float(s);
}

#if __has_builtin(__builtin_amdgcn_permlane16_swap)
__device__ __forceinline__ float xor16_add(float v) {
    u2v r = __builtin_amdgcn_permlane16_swap((unsigned)__float_as_int(v),
                                             (unsigned)__float_as_int(v),
                                             false, false);
    return __int_as_float((int)r.x) + __int_as_float((int)r.y);
}
#else
__device__ __forceinline__ float xor16_add(float v) {
    int s = __builtin_amdgcn_ds_swizzle(__float_as_int(v), 0x401F);
    return v + __int_as_float(s);
}
#endif

__device__ __forceinline__ float red32(float v) {
    v = dpp_xadd<0xB1>(v);    // lane ^ 1
    v = dpp_xadd<0x4E>(v);    // lane ^ 2
    v = dpp_xadd<0x141>(v);   // lane ^ 7
    v = dpp_xadd<0x140>(v);   // lane ^ 15
    v = xor16_add(v);         // lane ^ 16
    return v;
}

// ---- parallel precompute: tab[n] = (s, s*Cr, s*Ci, 0) -------------------
__global__ void pre_tab(const float* __restrict__ xre,
                        const float* __restrict__ xim,
                        float4* __restrict__ tab, int ns) {
    int n = blockIdx.x * blockDim.x + threadIdx.x;
    if (n >= ns) return;
    const float* ar = xre + 4 * n;
    const float* ai = xim + 4 * n;
    float un = 0.f;
    #pragma unroll 8
    for (int k = 0; k < 64; ++k) un = fmaf(ar[k], ar[k], fmaf(ai[k], ai[k], un));
    float s = (1.0f / 64.0f) / (un + 1e-8f);
    float cr = 0.f, ci = 0.f;
    if (n + 1 < ns) {
        const float* br_ = ar + 4;
        const float* bi_ = ai + 4;
        #pragma unroll 8
        for (int k = 0; k < 64; ++k) {
            cr = fmaf(ar[k], br_[k], fmaf(ai[k], bi_[k], cr));
            ci = fmaf(ar[k], bi_[k], ci);
            ci = fmaf(-ai[k], br_[k], ci);
        }
    }
    tab[n] = make_float4(s, s * cr, s * ci, 0.f);
}

#define NSTEPS 99985

// ---- 2-wave producer/consumer scan --------------------------------------
// wave0 (consumer): scalar chain per half; wave1 (producer): w + base.
// LDS: sh[2p+h] = bas (parity p, half h); sh[4+2p+h] = ews = s*ew.
// One barrier/step; parity double-buffer removes intra-step races.
__global__ __launch_bounds__(128, 1)
void ddlms_scan2(const float* __restrict__ xre,
                 const float* __restrict__ xim,
                 const float4* __restrict__ tab,
                 float* __restrict__ out) {
    const int tid = (int)threadIdx.x;
    const int wid = tid >> 6;
    const int l = tid & 63;
    const int m = l & 31;
    const int half = l >> 5;

    constexpr float EPSv = 1e-8f;
    constexpr float LRF  = 1.0f / 128.0f;
    constexpr float LRB  = 1.0f / 2048.0f;
    const float B1 = 0.6324555320336759f;
    const float A1 = 0.31622776601683794f;
    const float A3 = 0.9486832980505138f;

    __shared__ float2 sh[8];
    if (tid < 8) sh[tid] = make_float2(0.f, 0.f);
    __syncthreads();

    float2* __restrict__ o2 = reinterpret_cast<float2*>(out);

    if (wid == 0) {
        // ---------------- consumer: scalar chain ----------------
        float fr = 1.f, fi = 0.f, br = 0.f, bi = 0.f, psr = 1.f, psj = 0.f;
        float ewPr = 0.f, ewPi = 0.f, sCPr = 0.f, sCPi = 0.f;
        float4 t0 = tab[0], t1 = tab[1], t2 = tab[2], t3;

        auto W0 = [&](int n, int P, float4& tC, float4& tF) {
            __syncthreads();
            float2 bas = sh[2 * P + half];                 // bas_n (broadcast)
            float Dr = fmaf(ewPr, sCPr, -(ewPi * sCPi));   // D_{n-1}
            float Di = fmaf(ewPr, sCPi,   ewPi * sCPr);
            float vr = bas.x + Dr, vi = bas.y + Di;        // v_n
            { int nn = n + 3; if (nn > NSTEPS - 1) nn = NSTEPS - 1; tF = tab[nn]; }

            float kr = fmaf(vr, fr, -(vi * fi));
            float ki = fmaf(vr, fi,   vi * fr);
            float zr = kr + br, zi = ki + bi;
            if (m == 0) o2[2 * n + half] = make_float2(zr, zi);

            float magr = (fabsf(zr) > B1) ? A3 : A1;
            float dr   = (zr <= 0.f) ? -magr : magr;
            float magi = (fabsf(zi) > B1) ? A3 : A1;
            float di   = (zi <= 0.f) ? -magi : magi;

            float er = dr - zr, ei = di - zi;

            float v2  = fmaf(vr, vr, fmaf(vi, vi, EPSv));
            float rv  = __builtin_amdgcn_rcpf(v2);
            float gfr = fmaf(er, vr,   ei * vi)  * rv;
            float gfi = fmaf(ei, vr, -(er * vi)) * rv;
            float m2  = fmaf(gfr, gfr, gfi * gfi);
            float scf = fminf(1.f, 30.f * __builtin_amdgcn_rsqf(m2));
            float tf  = LRF * scf;

            float dbr = dr - br, dbi = di - bi;
            float ewr = fmaf(dbr, psr, -(dbi * psj)) - vr;
            float ewi = fmaf(dbr, psj,   dbi * psr)  - vi;

            float ewsr = tC.x * ewr, ewsi = tC.x * ewi;    // s_n * ew_n
            if (m == 0) sh[4 + 2 * P + half] = make_float2(ewsr, ewsi);

            fr = fmaf(tf, gfr, fr); fi = fmaf(tf, gfi, fi);
            br = fmaf(LRB, er, br); bi = fmaf(LRB, ei, bi);

            float ff = fmaf(fr, fr, fi * fi);
            float rs = __builtin_amdgcn_rsqf(ff);
            psr = fr * rs; psj = -(fi * rs);

            ewPr = ewr; ewPi = ewi; sCPr = tC.y; sCPi = tC.z;
        };

        int n = 0;
        for (int it = 0; it < 24996; ++it) {   // 4*24996 = 99984
            W0(n + 0, 0, t0, t3);
            W0(n + 1, 1, t1, t0);
            W0(n + 2, 0, t2, t1);
            W0(n + 3, 1, t3, t2);
            n += 4;
        }
        W0(99984, 0, t0, t3);                  // tail (99984 % 4 == 0)
    } else {
        // ---------------- producer: w + base ----------------
        float wAr = 0.f, wAi = 0.f, wBr = 0.f, wBi = 0.f;

        auto LOADU = [&](int nn, float& a, float& b_, float& c, float& d_) {
            const float* pr = xre + 4 * nn;
            const float* pi = xim + 4 * nn;
            a = pr[m]; c = pr[m + 32]; b_ = pi[m]; d_ = pi[m + 32];
        };

        float u0Ar, u0Ai, u0Br, u0Bi, u1Ar, u1Ai, u1Br, u1Bi,
              u2Ar, u2Ai, u2Br, u2Bi, u3Ar, u3Ai, u3Br, u3Bi;
        u3Ar = u3Ai = u3Br = u3Bi = 0.f;       // u_{-1} (ews_{-1} = 0)
        LOADU(0, u0Ar, u0Ai, u0Br, u0Bi);
        LOADU(1, u1Ar, u1Ai, u1Br, u1Bi);
        LOADU(2, u2Ar, u2Ai, u2Br, u2Bi);

        auto W1 = [&](int n, int P,
            float& uPAr, float& uPAi, float& uPBr, float& uPBi,
            float& uNAr, float& uNAi, float& uNBr, float& uNBi) {
            __syncthreads();
            float2 ews = sh[4 + 2 * (1 - P) + half];       // ews_{n-1}
            // w += ews (x) conj(uP)   [association change: wander class]
            wAr = fmaf(ews.x, uPAr, fmaf( ews.y, uPAi, wAr));
            wAi = fmaf(ews.y, uPAr, fmaf(-ews.x, uPAi, wAi));
            wBr = fmaf(ews.x, uPBr, fmaf( ews.y, uPBi, wBr));
            wBi = fmaf(ews.y, uPBr, fmaf(-ews.x, uPBi, wBi));
            // distance-3 prefetch into the now-dead uP slot
            { int nn = n + 3; if (nn > NSTEPS - 1) nn = NSTEPS - 1;
              LOADU(nn, uPAr, uPAi, uPBr, uPBi); }
            // bas_{n+1} = red(w_n * u_{n+1})
            float prr = wAr * uNAr; prr = fmaf(-wAi, uNAi, prr);
            prr = fmaf(wBr, uNBr, prr); prr = fmaf(-wBi, uNBi, prr);
            float pri = wAr * uNAi; pri = fmaf( wAi, uNAr, pri);
            pri = fmaf(wBr, uNBi, pri); pri = fmaf( wBi, uNBr, pri);
            float basr = red32(prr), basi = red32(pri);
            if (m == 0) sh[2 * (1 - P) + half] = make_float2(basr, basi);
        };

        int n = 0;
        for (int it = 0; it < 24996; ++it) {
            W1(n + 0, 0, u3Ar,u3Ai,u3Br,u3Bi, u1Ar,u1Ai,u1Br,u1Bi);
            W1(n + 1, 1, u0Ar,u0Ai,u0Br,u0Bi, u2Ar,u2Ai,u2Br,u2Bi);
            W1(n + 2, 0, u1Ar,u1Ai,u1Br,u1Bi, u3Ar,u3Ai,u3Br,u3Bi);
            W1(n + 3, 1, u2Ar,u2Ai,u2Br,u2Bi, u0Ar,u0Ai,u0Br,u0Bi);
            n += 4;
        }
        W1(99984, 0, u3Ar,u3Ai,u3Br,u3Bi, u1Ar,u1Ai,u1Br,u1Bi);
    }
}

// ---- fallback: single-wave in-kernel scalars (no workspace) -------------
__global__ __launch_bounds__(64, 1)
void ddlms_scan_fb(const float* __restrict__ xre,
                   const float* __restrict__ xim,
                   float* __restrict__ out) {
    const int l = (int)threadIdx.x;
    const int m = l & 31;
    const int half = l >> 5;
    constexpr float EPSv = 1e-8f;
    constexpr float LRW  = 1.0f / 64.0f;
    constexpr float LRF  = 1.0f / 128.0f;
    constexpr float LRB  = 1.0f / 2048.0f;
    const float B1 = 0.6324555320336759f;
    const float A1 = 0.31622776601683794f;
    const float A3 = 0.9486832980505138f;
    float wAr=0.f, wAi=0.f, wBr=0.f, wBi=0.f;
    float fr=1.f, fi=0.f, br=0.f, bi=0.f, psr=1.f, psj=0.f;
    float vr=0.f, vi=0.f, ewPr=0.f, ewPi=0.f, sP=0.f;
    float2* __restrict__ o2 = reinterpret_cast<float2*>(out);
    auto LOADU = [&](int nn, float& a, float& b_, float& c, float& d_) {
        const float* pr = xre + 4 * nn;
        const float* pi = xim + 4 * nn;
        a = pr[m]; c = pr[m + 32]; b_ = pi[m]; d_ = pi[m + 32];
    };
    float pAr,pAi,pBr,pBi, qAr,qAi,qBr,qBi, rAr,rAi,rBr,rBi;
    pAr=pAi=pBr=pBi=0.f;
    LOADU(0, qAr,qAi,qBr,qBi);
    LOADU(1, rAr,rAi,rBr,rBi);
    auto STEP = [&](int n,
        float& uPAr, float& uPAi, float& uPBr, float& uPBi,
        float& uCAr, float& uCAi, float& uCBr, float& uCBi,
        float& uNAr, float& uNAi, float& uNBr, float& uNBi) {
        {
            float gr = ewPr * uPAr; gr = fmaf( ewPi, uPAi, gr);
            float gi = ewPi * uPAr; gi = fmaf(-ewPr, uPAi, gi);
            wAr = fmaf(sP, gr, wAr); wAi = fmaf(sP, gi, wAi);
            float hr = ewPr * uPBr; hr = fmaf( ewPi, uPBi, hr);
            float hi = ewPi * uPBr; hi = fmaf(-ewPr, uPBi, hi);
            wBr = fmaf(sP, hr, wBr); wBi = fmaf(sP, hi, wBi);
        }
        float basr, basi;
        {
            float prr = wAr * uNAr; prr = fmaf(-wAi, uNAi, prr);
            prr = fmaf(wBr, uNBr, prr); prr = fmaf(-wBi, uNBi, prr);
            float pri = wAr * uNAi; pri = fmaf( wAi, uNAr, pri);
            pri = fmaf(wBr, uNBi, pri); pri = fmaf( wBi, uNBr, pri);
            basr = red32(prr); basi = red32(pri);
        }
        float uu = uCAr*uCAr; uu = fmaf(uCAi,uCAi,uu);
        uu = fmaf(uCBr,uCBr,uu); uu = fmaf(uCBi,uCBi,uu);
        float sN = LRW * __builtin_amdgcn_rcpf(red32(uu) + EPSv);
        float ccr = uCAr*uNAr; ccr = fmaf(uCAi,uNAi,ccr);
        ccr = fmaf(uCBr,uNBr,ccr); ccr = fmaf(uCBi,uNBi,ccr);
        float cci = uCAr*uNAi; cci = fmaf(-uCAi,uNAr,cci);
        cci = fmaf(uCBr,uNBi,cci); cci = fmaf(-uCBi,uNBr,cci);
        float sCr = sN * red32(ccr), sCi = sN * red32(cci);
        float kr = fmaf(vr, fr, -(vi * fi));
        float ki = fmaf(vr, fi,   vi * fr);
        float zr = kr + br, zi = ki + bi;
        if (m == 0) o2[2 * n + half] = make_float2(zr, zi);
        float magr = (fabsf(zr) > B1) ? A3 : A1;
        float dr   = (zr <= 0.f) ? -magr : magr;
        float magi = (fabsf(zi) > B1) ? A3 : A1;
        float di   = (zi <= 0.f) ? -magi : magi;
        float er = dr - zr, ei = di - zi;
        float v2  = fmaf(vr, vr, fmaf(vi, vi, EPSv));
        float rv  = __builtin_amdgcn_rcpf(v2);
        float gfr = fmaf(er, vr,   ei * vi)  * rv;
        float gfi = fmaf(ei, vr, -(er * vi)) * rv;
        float m2  = fmaf(gfr, gfr, gfi * gfi);
        float scf = fminf(1.f, 30.f * __builtin_amdgcn_rsqf(m2));
        float tf  = LRF * scf;
        float dbr = dr - br, dbi = di - bi;
        float ewr = fmaf(dbr, psr, -(dbi * psj)) - vr;
        float ewi = fmaf(dbr, psj,   dbi * psr)  - vi;
        float Dr = fmaf(ewr, sCr, -(ewi * sCi));
        float Di = fmaf(ewr, sCi,   ewi * sCr);
        vr = basr + Dr; vi = basi + Di;
        fr = fmaf(tf, gfr, fr); fi = fmaf(tf, gfi, fi);
        br = fmaf(LRB, er, br); bi = fmaf(LRB, ei, bi);
        float ff = fmaf(fr, fr, fi * fi);
        float rs = __builtin_amdgcn_rsqf(ff);
        psr = fr * rs; psj = -(fi * rs);
        ewPr = ewr; ewPi = ewi; sP = sN;
        int nn = n + 2; if (nn > NSTEPS - 1) nn = NSTEPS - 1;
        LOADU(nn, uPAr, uPAi, uPBr, uPBi);
    };
    int n = 0;
    for (int it = 0; it < 33328; ++it) {
        STEP(n,     pAr,pAi,pBr,pBi,  qAr,qAi,qBr,qBi,  rAr,rAi,rBr,rBi);
        STEP(n + 1, qAr,qAi,qBr,qBi,  rAr,rAi,rBr,rBi,  pAr,pAi,pBr,pBi);
        STEP(n + 2, rAr,rAi,rBr,rBi,  pAr,pAi,pBr,pBi,  qAr,qAi,qBr,qBi);
        n += 3;
    }
    STEP(99984, pAr,pAi,pBr,pBi, qAr,qAi,qBr,qBi, rAr,rAi,rBr,rBi);
}

extern "C" void kernel_launch(void* const* d_in, const int* in_sizes, int n_in,
                              void* d_out, int out_size, void* d_ws, size_t ws_size,
                              hipStream_t stream) {
    const float* xre = (const float*)d_in[0];
    const float* xim = (const float*)d_in[1];
    float* out = (float*)d_out;
    const int NS = NSTEPS;

    if (ws_size >= (size_t)NS * sizeof(float4)) {
        float4* tab = (float4*)d_ws;
        pre_tab<<<(NS + 255) / 256, 256, 0, stream>>>(xre, xim, tab, NS);
        ddlms_scan2<<<1, 128, 0, stream>>>(xre, xim, tab, out);
    } else {
        ddlms_scan_fb<<<1, 64, 0, stream>>>(xre, xim, out);
    }
}